// Round 1
// baseline (629.490 us; speedup 1.0000x reference)
//
#include <hip/hip_runtime.h>

#define IN_FEAT 128
#define HEADS 8
#define OUT_FEAT 16
#define HF 128  // HEADS*OUT_FEAT

// ---------------- K1: h = feat @ W_fc  and  post[n][k][h] ----------------
// block=256, 32 nodes/block. thread: cg=tid&31 (4 cols), ng=tid>>5 (4 nodes)
__global__ __launch_bounds__(256) void gemm_post_kernel(
    const float* __restrict__ feat, const float* __restrict__ W_fc,
    const float* __restrict__ W_post, const float* __restrict__ b_post,
    float* __restrict__ hbuf, float* __restrict__ post, int N)
{
    __shared__ float4 lds4[32 * 32];          // 32 nodes x 128 feats (16 KB)
    float* lds = (float*)lds4;
    const int tid = threadIdx.x;
    const int node_base = blockIdx.x * 32;

    // stage feat rows (coalesced float4)
    const float4* f4 = (const float4*)feat;
    for (int i = tid; i < 32 * 32; i += 256) {
        int n = i >> 5, k4 = i & 31;
        int gn = node_base + n;
        float4 v = make_float4(0.f, 0.f, 0.f, 0.f);
        if (gn < N) v = f4[gn * 32 + k4];
        lds4[i] = v;
    }
    __syncthreads();

    const int cg = tid & 31, ng = tid >> 5;
    const int n0 = ng * 4;
    float acc[4][4];
#pragma unroll
    for (int i = 0; i < 4; i++) acc[i][0] = acc[i][1] = acc[i][2] = acc[i][3] = 0.f;

    const float4* W4 = (const float4*)W_fc;
#pragma unroll 4
    for (int k = 0; k < 128; ++k) {
        float4 w = W4[k * 32 + cg];
#pragma unroll
        for (int i = 0; i < 4; i++) {
            float f = lds[(n0 + i) * 128 + k];  // broadcast within wave (free)
            acc[i][0] += f * w.x; acc[i][1] += f * w.y;
            acc[i][2] += f * w.z; acc[i][3] += f * w.w;
        }
    }
    // store h
#pragma unroll
    for (int i = 0; i < 4; i++) {
        int gn = node_base + n0 + i;
        if (gn < N)
            ((float4*)hbuf)[gn * 32 + cg] =
                make_float4(acc[i][0], acc[i][1], acc[i][2], acc[i][3]);
    }
    __syncthreads();   // done reading feat from lds
    // put h into lds for the post computation
#pragma unroll
    for (int i = 0; i < 4; i++)
        lds4[(n0 + i) * 32 + cg] = make_float4(acc[i][0], acc[i][1], acc[i][2], acc[i][3]);
    __syncthreads();

    // post params: tid -> n = tid>>3 (0..31), h = tid&7
    {
        int n = tid >> 3, h = tid & 7;
        float p0 = b_post[0], p1 = b_post[1], p2 = b_post[2], p3 = b_post[3];
#pragma unroll
        for (int f = 0; f < 16; ++f) {
            float v = lds[n * 128 + h * 16 + f];
            p0 += v * W_post[f * 4 + 0];
            p1 += v * W_post[f * 4 + 1];
            p2 += v * W_post[f * 4 + 2];
            p3 += v * W_post[f * 4 + 3];
        }
        int gn = node_base + n;
        if (gn < N) {
            // layout post[n][k][h], k: 0=loc_l 1=loc_r 2=lsl 3=lsr
            post[gn * 32 + 0 * 8 + h] = p0;
            post[gn * 32 + 1 * 8 + h] = p1;
            post[gn * 32 + 2 * 8 + h] = p2;
            post[gn * 32 + 3 * 8 + h] = p3;
        }
    }
}

// ---------------- K2: histogram of dst ----------------
__global__ __launch_bounds__(256) void hist_kernel(const int* __restrict__ dst,
                                                   int* __restrict__ counts, int E)
{
    int g = blockIdx.x * 256 + threadIdx.x;
    if (g < E) atomicAdd(&counts[dst[g]], 1);
}

// ---------------- K3a: per-256-chunk sums ----------------
__global__ __launch_bounds__(256) void block_sum_kernel(const int* __restrict__ counts,
                                                        int* __restrict__ blockSums, int N)
{
    __shared__ int sd[256];
    int tid = threadIdx.x;
    int g = blockIdx.x * 256 + tid;
    sd[tid] = (g < N) ? counts[g] : 0;
    __syncthreads();
    for (int off = 128; off > 0; off >>= 1) {
        if (tid < off) sd[tid] += sd[tid + off];
        __syncthreads();
    }
    if (tid == 0) blockSums[blockIdx.x] = sd[0];
}

// ---------------- K3b: exclusive scan of block sums (single block) ----------------
__global__ __launch_bounds__(256) void scan_sums_kernel(const int* __restrict__ blockSums,
                                                        int* __restrict__ blockOffs, int nb)
{
    __shared__ int sd[256];
    int tid = threadIdx.x;
    int v = (tid < nb) ? blockSums[tid] : 0;
    sd[tid] = v;
    __syncthreads();
    for (int off = 1; off < 256; off <<= 1) {
        int t = (tid >= off) ? sd[tid - off] : 0;
        __syncthreads();
        sd[tid] += t;
        __syncthreads();
    }
    if (tid < nb) blockOffs[tid] = sd[tid] - v;
}

// ---------------- K3c: per-chunk exclusive scan -> offsets, cursor ----------------
__global__ __launch_bounds__(256) void scan_block_kernel(
    const int* __restrict__ counts, const int* __restrict__ blockOffs,
    int* __restrict__ offsets, int* __restrict__ cursor, int N, int E)
{
    __shared__ int sd[256];
    int tid = threadIdx.x;
    int g = blockIdx.x * 256 + tid;
    int v = (g < N) ? counts[g] : 0;
    sd[tid] = v;
    __syncthreads();
    for (int off = 1; off < 256; off <<= 1) {
        int t = (tid >= off) ? sd[tid - off] : 0;
        __syncthreads();
        sd[tid] += t;
        __syncthreads();
    }
    if (g < N) {
        int o = blockOffs[blockIdx.x] + sd[tid] - v;
        offsets[g] = o;
        cursor[g] = o;
    }
    if (g == N) offsets[N] = E;
}

// ---------------- K4: scatter edge ids into CSR order ----------------
__global__ __launch_bounds__(256) void scatter_kernel(const int* __restrict__ dst,
                                                      int* __restrict__ cursor,
                                                      int* __restrict__ perm, int E)
{
    int g = blockIdx.x * 256 + threadIdx.x;
    if (g < E) {
        int d = dst[g];
        int pos = atomicAdd(&cursor[d], 1);
        perm[pos] = g;
    }
}

// ---------------- K5: denom[d][h] = sum exp(e) over in-edges ----------------
__global__ __launch_bounds__(256) void denom_kernel(
    const int* __restrict__ src, const int* __restrict__ dst,
    const float* __restrict__ eps, const float* __restrict__ post,
    float* __restrict__ denom, int E)
{
    int g = blockIdx.x * 256 + threadIdx.x;
    int e = g >> 3, h = g & 7;
    if (e >= E) return;
    int s = src[e], d = dst[e];
    float ll = post[s * 32 + h];
    float lr = post[d * 32 + 8 + h];
    float sl = post[s * 32 + 16 + h];
    float sr = post[d * 32 + 24 + h];
    float ev = (ll + lr) + __expf(sl + sr) * eps[e * 8 + h];
    atomicAdd(&denom[d * 8 + h], __expf(ev));
}

// ---------------- K6: per-node aggregation (atomic-free) ----------------
// block = 128 threads = one dst node; thread t -> (h = t>>4, f = t&15)
__global__ __launch_bounds__(128) void agg_kernel(
    const int* __restrict__ src, const int* __restrict__ perm,
    const int* __restrict__ offsets, const float* __restrict__ eps,
    const float* __restrict__ post, const float* __restrict__ denom,
    const float* __restrict__ hbuf, const float* __restrict__ bias,
    float* __restrict__ out)
{
    __shared__ float a_lds[16 * 8];
    __shared__ int   s_lds[16];
    __shared__ float locr[8], lsr8[8], dinv[8];
    const int d = blockIdx.x;
    const int tid = threadIdx.x;
    if (tid < 8) {
        locr[tid] = post[d * 32 + 8 + tid];
        lsr8[tid] = post[d * 32 + 24 + tid];
        float dn = denom[d * 8 + tid];
        dinv[tid] = (dn > 0.f) ? 1.f / dn : 0.f;
    }
    const int start = offsets[d];
    const int deg = offsets[d + 1] - start;
    __syncthreads();

    float acc = 0.f;
    const int h_t = tid >> 4;
    for (int c = 0; c < deg; c += 16) {
        int jcount = min(16, deg - c);
        int j = tid >> 3, h = tid & 7;
        if (j < jcount) {
            int edge = perm[start + c + j];
            int s = src[edge];
            float ev = (post[s * 32 + h] + locr[h]) +
                       __expf(post[s * 32 + 16 + h] + lsr8[h]) * eps[edge * 8 + h];
            a_lds[j * 8 + h] = __expf(ev) * dinv[h];
            if (h == 0) s_lds[j] = s;
        }
        __syncthreads();
        for (int j2 = 0; j2 < jcount; ++j2)
            acc += a_lds[j2 * 8 + h_t] * hbuf[s_lds[j2] * 128 + tid];
        __syncthreads();
    }
    out[d * 128 + tid] = acc + bias[tid];
}

extern "C" void kernel_launch(void* const* d_in, const int* in_sizes, int n_in,
                              void* d_out, int out_size, void* d_ws, size_t ws_size,
                              hipStream_t stream)
{
    const float* feat   = (const float*)d_in[0];
    const int*   src    = (const int*)d_in[1];
    const int*   dst    = (const int*)d_in[2];
    const float* eps    = (const float*)d_in[3];
    const float* W_fc   = (const float*)d_in[4];
    const float* W_post = (const float*)d_in[5];
    const float* b_post = (const float*)d_in[6];
    const float* bias   = (const float*)d_in[7];
    float* out = (float*)d_out;

    const int N = in_sizes[0] / IN_FEAT;   // 50000
    const int E = in_sizes[1];             // 1600000

    // workspace layout (256B-aligned segments), total ~41 MB
    char* p = (char*)d_ws;
    auto alloc = [&](size_t bytes) {
        char* r = p;
        p += (bytes + 255) & ~size_t(255);
        return r;
    };
    float* hbuf    = (float*)alloc((size_t)N * HF * 4);
    float* post    = (float*)alloc((size_t)N * 32 * 4);
    float* denom   = (float*)alloc((size_t)N * 8 * 4);
    int*   counts  = (int*)alloc((size_t)N * 4);
    int*   offsets = (int*)alloc((size_t)(N + 1) * 4);
    int*   cursor  = (int*)alloc((size_t)N * 4);
    int*   blockSums = (int*)alloc(1024);
    int*   blockOffs = (int*)alloc(1024);
    int*   perm    = (int*)alloc((size_t)E * 4);

    hipMemsetAsync(counts, 0, (size_t)N * 4, stream);
    hipMemsetAsync(denom, 0, (size_t)N * 8 * 4, stream);

    const int nbScan = (N + 255) / 256;  // 196

    gemm_post_kernel<<<(N + 31) / 32, 256, 0, stream>>>(feat, W_fc, W_post, b_post,
                                                        hbuf, post, N);
    hist_kernel<<<(E + 255) / 256, 256, 0, stream>>>(dst, counts, E);
    block_sum_kernel<<<nbScan, 256, 0, stream>>>(counts, blockSums, N);
    scan_sums_kernel<<<1, 256, 0, stream>>>(blockSums, blockOffs, nbScan);
    scan_block_kernel<<<nbScan, 256, 0, stream>>>(counts, blockOffs, offsets, cursor, N, E);
    scatter_kernel<<<(E + 255) / 256, 256, 0, stream>>>(dst, cursor, perm, E);
    denom_kernel<<<(int)(((size_t)E * 8 + 255) / 256), 256, 0, stream>>>(src, dst, eps,
                                                                         post, denom, E);
    agg_kernel<<<N, 128, 0, stream>>>(src, perm, offsets, eps, post, denom, hbuf, bias, out);
}

// Round 2
// 437.130 us; speedup vs baseline: 1.4401x; 1.4401x over previous
//
#include <hip/hip_runtime.h>
#include <hip/hip_fp16.h>

#define IN_FEAT 128
#define HEADS 8
#define OUT_FEAT 16
#define HF 128  // HEADS*OUT_FEAT

// ---------------- K1: h = feat @ W_fc (fp16 out) and post[n][k][h] (fp32) ----
// block=256, 32 nodes/block. thread: cg=tid&31 (4 cols), ng=tid>>5 (4 nodes)
__global__ __launch_bounds__(256) void gemm_post_kernel(
    const float* __restrict__ feat, const float* __restrict__ W_fc,
    const float* __restrict__ W_post, const float* __restrict__ b_post,
    __half* __restrict__ hbuf, float* __restrict__ post, int N)
{
    __shared__ float4 lds4[32 * 32];          // 32 nodes x 128 feats (16 KB)
    float* lds = (float*)lds4;
    const int tid = threadIdx.x;
    const int node_base = blockIdx.x * 32;

    const float4* f4 = (const float4*)feat;
    for (int i = tid; i < 32 * 32; i += 256) {
        int n = i >> 5, k4 = i & 31;
        int gn = node_base + n;
        float4 v = make_float4(0.f, 0.f, 0.f, 0.f);
        if (gn < N) v = f4[gn * 32 + k4];
        lds4[i] = v;
    }
    __syncthreads();

    const int cg = tid & 31, ng = tid >> 5;
    const int n0 = ng * 4;
    float acc[4][4];
#pragma unroll
    for (int i = 0; i < 4; i++) acc[i][0] = acc[i][1] = acc[i][2] = acc[i][3] = 0.f;

    const float4* W4 = (const float4*)W_fc;
#pragma unroll 4
    for (int k = 0; k < 128; ++k) {
        float4 w = W4[k * 32 + cg];
#pragma unroll
        for (int i = 0; i < 4; i++) {
            float f = lds[(n0 + i) * 128 + k];
            acc[i][0] += f * w.x; acc[i][1] += f * w.y;
            acc[i][2] += f * w.z; acc[i][3] += f * w.w;
        }
    }
    // store h as fp16 (one 8B store per node-row chunk)
    __half2* hb2 = (__half2*)hbuf;
#pragma unroll
    for (int i = 0; i < 4; i++) {
        int gn = node_base + n0 + i;
        if (gn < N) {
            union { uint2 u; __half2 h[2]; } pk;
            pk.h[0] = __floats2half2_rn(acc[i][0], acc[i][1]);
            pk.h[1] = __floats2half2_rn(acc[i][2], acc[i][3]);
            *(uint2*)&hb2[gn * 64 + cg * 2] = pk.u;
        }
    }
    __syncthreads();   // done reading feat from lds
#pragma unroll
    for (int i = 0; i < 4; i++)
        lds4[(n0 + i) * 32 + cg] = make_float4(acc[i][0], acc[i][1], acc[i][2], acc[i][3]);
    __syncthreads();

    {
        int n = tid >> 3, h = tid & 7;
        float p0 = b_post[0], p1 = b_post[1], p2 = b_post[2], p3 = b_post[3];
#pragma unroll
        for (int f = 0; f < 16; ++f) {
            float v = lds[n * 128 + h * 16 + f];
            p0 += v * W_post[f * 4 + 0];
            p1 += v * W_post[f * 4 + 1];
            p2 += v * W_post[f * 4 + 2];
            p3 += v * W_post[f * 4 + 3];
        }
        int gn = node_base + n;
        if (gn < N) {
            // layout post[n][k][h], k: 0=loc_l 1=loc_r 2=lsl 3=lsr
            post[gn * 32 + 0 * 8 + h] = p0;
            post[gn * 32 + 1 * 8 + h] = p1;
            post[gn * 32 + 2 * 8 + h] = p2;
            post[gn * 32 + 3 * 8 + h] = p3;
        }
    }
}

// ---------------- K2: histogram of dst ----------------
__global__ __launch_bounds__(256) void hist_kernel(const int* __restrict__ dst,
                                                   int* __restrict__ counts, int E)
{
    int g = blockIdx.x * 256 + threadIdx.x;
    if (g < E) atomicAdd(&counts[dst[g]], 1);
}

// ---------------- K3a: per-256-chunk sums ----------------
__global__ __launch_bounds__(256) void block_sum_kernel(const int* __restrict__ counts,
                                                        int* __restrict__ blockSums, int N)
{
    __shared__ int sd[256];
    int tid = threadIdx.x;
    int g = blockIdx.x * 256 + tid;
    sd[tid] = (g < N) ? counts[g] : 0;
    __syncthreads();
    for (int off = 128; off > 0; off >>= 1) {
        if (tid < off) sd[tid] += sd[tid + off];
        __syncthreads();
    }
    if (tid == 0) blockSums[blockIdx.x] = sd[0];
}

// ---------------- K3b: exclusive scan of block sums (single block) ----------------
__global__ __launch_bounds__(256) void scan_sums_kernel(const int* __restrict__ blockSums,
                                                        int* __restrict__ blockOffs, int nb)
{
    __shared__ int sd[256];
    int tid = threadIdx.x;
    int v = (tid < nb) ? blockSums[tid] : 0;
    sd[tid] = v;
    __syncthreads();
    for (int off = 1; off < 256; off <<= 1) {
        int t = (tid >= off) ? sd[tid - off] : 0;
        __syncthreads();
        sd[tid] += t;
        __syncthreads();
    }
    if (tid < nb) blockOffs[tid] = sd[tid] - v;
}

// ---------------- K3c: per-chunk exclusive scan -> offsets, cursor ----------------
__global__ __launch_bounds__(256) void scan_block_kernel(
    const int* __restrict__ counts, const int* __restrict__ blockOffs,
    int* __restrict__ offsets, int* __restrict__ cursor, int N, int E)
{
    __shared__ int sd[256];
    int tid = threadIdx.x;
    int g = blockIdx.x * 256 + tid;
    int v = (g < N) ? counts[g] : 0;
    sd[tid] = v;
    __syncthreads();
    for (int off = 1; off < 256; off <<= 1) {
        int t = (tid >= off) ? sd[tid - off] : 0;
        __syncthreads();
        sd[tid] += t;
        __syncthreads();
    }
    if (g < N) {
        int o = blockOffs[blockIdx.x] + sd[tid] - v;
        offsets[g] = o;
        cursor[g] = o;
    }
    if (g == N) offsets[N] = E;
}

// ---------------- K4: fused edge pass ----------------
// per edge: compute ex[h]=exp(e) for 8 heads, claim CSR slot, write
// perm[pos]=src and exbuf[pos][0..7] (fp16, one 16B store).
__global__ __launch_bounds__(256) void edge_kernel(
    const int* __restrict__ src, const int* __restrict__ dst,
    const float* __restrict__ eps, const float* __restrict__ post,
    int* __restrict__ cursor, int* __restrict__ perm,
    __half* __restrict__ exbuf, int E)
{
    int e = blockIdx.x * 256 + threadIdx.x;
    if (e >= E) return;
    int s = src[e], d = dst[e];
    const float4* p4 = (const float4*)post;   // post row = 8 float4
    float4 ll0 = p4[s * 8 + 0], ll1 = p4[s * 8 + 1];   // loc_l[0..7]
    float4 sl0 = p4[s * 8 + 4], sl1 = p4[s * 8 + 5];   // lsl[0..7]
    float4 lr0 = p4[d * 8 + 2], lr1 = p4[d * 8 + 3];   // loc_r[0..7]
    float4 sr0 = p4[d * 8 + 6], sr1 = p4[d * 8 + 7];   // lsr[0..7]
    const float4* e4 = (const float4*)eps + (size_t)e * 2;
    float4 ep0 = e4[0], ep1 = e4[1];

    float ll[8] = {ll0.x, ll0.y, ll0.z, ll0.w, ll1.x, ll1.y, ll1.z, ll1.w};
    float sl[8] = {sl0.x, sl0.y, sl0.z, sl0.w, sl1.x, sl1.y, sl1.z, sl1.w};
    float lr[8] = {lr0.x, lr0.y, lr0.z, lr0.w, lr1.x, lr1.y, lr1.z, lr1.w};
    float sr[8] = {sr0.x, sr0.y, sr0.z, sr0.w, sr1.x, sr1.y, sr1.z, sr1.w};
    float ep[8] = {ep0.x, ep0.y, ep0.z, ep0.w, ep1.x, ep1.y, ep1.z, ep1.w};

    float ex[8];
#pragma unroll
    for (int h = 0; h < 8; ++h) {
        float ev = (ll[h] + lr[h]) + __expf(sl[h] + sr[h]) * ep[h];
        ex[h] = __expf(ev);
    }
    int pos = atomicAdd(&cursor[d], 1);
    perm[pos] = s;
    union { float4 f4; __half2 h2[4]; } pk;
#pragma unroll
    for (int h = 0; h < 4; ++h)
        pk.h2[h] = __floats2half2_rn(ex[2 * h], ex[2 * h + 1]);
    ((float4*)exbuf)[pos] = pk.f4;
}

// ---------------- K5: per-node aggregation (atomic-free, self-normalizing) ---
// block = 128 threads = one dst node; thread t -> (h = t>>4, f = t&15)
__global__ __launch_bounds__(128) void agg_kernel(
    const int* __restrict__ perm_src, const int* __restrict__ offsets,
    const __half* __restrict__ exbuf, const __half* __restrict__ hbuf,
    const float* __restrict__ bias, float* __restrict__ out)
{
    __shared__ float a_lds[16 * 8];
    __shared__ int   s_lds[16];
    const int d = blockIdx.x;
    const int tid = threadIdx.x;
    const int start = offsets[d];
    const int deg = offsets[d + 1] - start;

    float acc = 0.f, dsum = 0.f;
    const int h_t = tid >> 4;
    for (int c = 0; c < deg; c += 16) {
        int jcount = min(16, deg - c);
        if (tid < jcount) s_lds[tid] = perm_src[start + c + tid];
        int nh = jcount * 8;
        if (tid < nh) a_lds[tid] = __half2float(exbuf[(size_t)(start + c) * 8 + tid]);
        __syncthreads();
        for (int j2 = 0; j2 < jcount; ++j2) {
            float a = a_lds[j2 * 8 + h_t];
            acc += a * __half2float(hbuf[(size_t)s_lds[j2] * 128 + tid]);
            dsum += a;
        }
        __syncthreads();
    }
    float r = (dsum > 0.f) ? acc / dsum : 0.f;
    out[d * 128 + tid] = r + bias[tid];
}

extern "C" void kernel_launch(void* const* d_in, const int* in_sizes, int n_in,
                              void* d_out, int out_size, void* d_ws, size_t ws_size,
                              hipStream_t stream)
{
    const float* feat   = (const float*)d_in[0];
    const int*   src    = (const int*)d_in[1];
    const int*   dst    = (const int*)d_in[2];
    const float* eps    = (const float*)d_in[3];
    const float* W_fc   = (const float*)d_in[4];
    const float* W_post = (const float*)d_in[5];
    const float* b_post = (const float*)d_in[6];
    const float* bias   = (const float*)d_in[7];
    float* out = (float*)d_out;

    const int N = in_sizes[0] / IN_FEAT;   // 50000
    const int E = in_sizes[1];             // 1600000

    // workspace layout (256B-aligned segments), total ~52 MB
    char* p = (char*)d_ws;
    auto alloc = [&](size_t bytes) {
        char* r = p;
        p += (bytes + 255) & ~size_t(255);
        return r;
    };
    __half* hbuf   = (__half*)alloc((size_t)N * HF * 2);      // 12.8 MB fp16
    float*  post   = (float*)alloc((size_t)N * 32 * 4);       // 6.4 MB
    int*    counts = (int*)alloc((size_t)N * 4);
    int*    offsets= (int*)alloc((size_t)(N + 1) * 4);
    int*    cursor = (int*)alloc((size_t)N * 4);
    int*    blockSums = (int*)alloc(1024);
    int*    blockOffs = (int*)alloc(1024);
    int*    perm   = (int*)alloc((size_t)E * 4);              // 6.4 MB (holds src ids)
    __half* exbuf  = (__half*)alloc((size_t)E * 8 * 2);       // 25.6 MB

    hipMemsetAsync(counts, 0, (size_t)N * 4, stream);

    const int nbScan = (N + 255) / 256;  // 196

    gemm_post_kernel<<<(N + 31) / 32, 256, 0, stream>>>(feat, W_fc, W_post, b_post,
                                                        hbuf, post, N);
    hist_kernel<<<(E + 255) / 256, 256, 0, stream>>>(dst, counts, E);
    block_sum_kernel<<<nbScan, 256, 0, stream>>>(counts, blockSums, N);
    scan_sums_kernel<<<1, 256, 0, stream>>>(blockSums, blockOffs, nbScan);
    scan_block_kernel<<<nbScan, 256, 0, stream>>>(counts, blockOffs, offsets, cursor, N, E);
    edge_kernel<<<(E + 255) / 256, 256, 0, stream>>>(src, dst, eps, post, cursor,
                                                     perm, exbuf, E);
    agg_kernel<<<N, 128, 0, stream>>>(perm, offsets, exbuf, hbuf, bias, out);
}